// Round 6
// baseline (604.829 us; speedup 1.0000x reference)
//
#include <hip/hip_runtime.h>
#include <hip/hip_bf16.h>
#include <stdint.h>

#define D_MODEL 1024
#define NHEAD   16
#define HDIM    64
#define SEQ     2048
#define BH      64   // 4 batches * 16 heads

typedef short bf16x8 __attribute__((ext_vector_type(8)));
typedef float f32x4  __attribute__((ext_vector_type(4)));

static __device__ __forceinline__ float bf2f(ushort u) {
    union { uint32_t i; float f; } v; v.i = ((uint32_t)u) << 16; return v.f;
}
static __device__ __forceinline__ ushort f2bf(float f) {
    __hip_bfloat16 h = __float2bfloat16(f);
    union { __hip_bfloat16 h; ushort u; } v; v.h = h; return v.u;
}
static __device__ __forceinline__ uint32_t pk2(float a, float b) {
    return (uint32_t)f2bf(a) | ((uint32_t)f2bf(b) << 16);
}
// Load 8 fp32, convert to bf16 (RNE), store 16B to LDS.
static __device__ __forceinline__ void cvt_store8(ushort* dst, const float* src) {
    float4 a = *(const float4*)src;
    float4 b = *(const float4*)(src + 4);
    uint4 o;
    o.x = pk2(a.x, a.y);
    o.y = pk2(a.z, a.w);
    o.z = pk2(b.x, b.y);
    o.w = pk2(b.z, b.w);
    *(uint4*)dst = o;
}

// ---------------------------------------------------------------------------
// GEMM1: qkv = X[8192,1024](f32) * Wqkv[3072,1024](f32)^T, bf16 MFMA compute.
// Scatter epilogue: q,k -> [bh][s][d] bf16 ; v -> transposed [bh][d][s] bf16.
// ---------------------------------------------------------------------------
__global__ __launch_bounds__(256)
void gemm_qkv(const float* __restrict__ X, const float* __restrict__ W,
              ushort* __restrict__ qb, ushort* __restrict__ kb,
              ushort* __restrict__ vt)
{
    __shared__ ushort As[128 * 72];
    __shared__ ushort Bs[128 * 72];
    const int K = 1024;
    const int m0 = blockIdx.y * 128;
    const int n0 = blockIdx.x * 128;
    const int t = threadIdx.x;
    const int lane = t & 63, wv = t >> 6;
    const int wm = (wv >> 1) * 64, wn = (wv & 1) * 64;
    const int l15 = lane & 15, quad = lane >> 4;

    f32x4 acc[4][4];
#pragma unroll
    for (int i = 0; i < 4; i++)
#pragma unroll
        for (int j = 0; j < 4; j++) acc[i][j] = (f32x4){0.f, 0.f, 0.f, 0.f};

    for (int k0 = 0; k0 < K; k0 += 64) {
        __syncthreads();
#pragma unroll
        for (int i = 0; i < 4; i++) {
            int slot = t + 256 * i;
            int r = slot >> 3, c = (slot & 7) * 8;
            cvt_store8(&As[r * 72 + c], &X[(size_t)(m0 + r) * K + k0 + c]);
            cvt_store8(&Bs[r * 72 + c], &W[(size_t)(n0 + r) * K + k0 + c]);
        }
        __syncthreads();
#pragma unroll
        for (int ks = 0; ks < 2; ks++) {
            bf16x8 af[4], bfr[4];
            const int kc = ks * 32 + quad * 8;
#pragma unroll
            for (int mi = 0; mi < 4; mi++)
                af[mi] = *(const bf16x8*)&As[(wm + mi * 16 + l15) * 72 + kc];
#pragma unroll
            for (int ni = 0; ni < 4; ni++)
                bfr[ni] = *(const bf16x8*)&Bs[(wn + ni * 16 + l15) * 72 + kc];
#pragma unroll
            for (int ni = 0; ni < 4; ni++)
#pragma unroll
                for (int mi = 0; mi < 4; mi++)
                    acc[mi][ni] = __builtin_amdgcn_mfma_f32_16x16x32_bf16(
                        af[mi], bfr[ni], acc[mi][ni], 0, 0, 0);
        }
    }

#pragma unroll
    for (int ni = 0; ni < 4; ni++) {
        const int e = n0 + wn + ni * 16 + l15;
        const int which = e >> 10;
        const int h = (e >> 6) & 15;
        const int d = e & 63;
#pragma unroll
        for (int mi = 0; mi < 4; mi++) {
            const int gm0 = m0 + wm + mi * 16 + quad * 4;
            const int b = gm0 >> 11;
            const int s0 = gm0 & 2047;
            const int bh = b * NHEAD + h;
            if (which == 2) {
                ushort4 pk;
                pk.x = f2bf(acc[mi][ni][0]); pk.y = f2bf(acc[mi][ni][1]);
                pk.z = f2bf(acc[mi][ni][2]); pk.w = f2bf(acc[mi][ni][3]);
                *(ushort4*)&vt[((size_t)bh * HDIM + d) * SEQ + s0] = pk;
            } else {
                ushort* dst = (which == 0) ? qb : kb;
#pragma unroll
                for (int r = 0; r < 4; r++)
                    dst[((size_t)bh * SEQ + s0 + r) * HDIM + d] = f2bf(acc[mi][ni][r]);
            }
        }
    }
}

// ---------------------------------------------------------------------------
// GEMM2: out(f32) = A[8192,1024](bf16) * Wout[1024,1024](f32)^T
// ---------------------------------------------------------------------------
__global__ __launch_bounds__(256)
void gemm_out(const ushort* __restrict__ A, const float* __restrict__ W,
              float* __restrict__ out)
{
    __shared__ ushort As[128 * 72];
    __shared__ ushort Bs[128 * 72];
    const int K = 1024;
    const int m0 = blockIdx.y * 128;
    const int n0 = blockIdx.x * 128;
    const int t = threadIdx.x;
    const int lane = t & 63, wv = t >> 6;
    const int wm = (wv >> 1) * 64, wn = (wv & 1) * 64;
    const int l15 = lane & 15, quad = lane >> 4;

    f32x4 acc[4][4];
#pragma unroll
    for (int i = 0; i < 4; i++)
#pragma unroll
        for (int j = 0; j < 4; j++) acc[i][j] = (f32x4){0.f, 0.f, 0.f, 0.f};

    for (int k0 = 0; k0 < K; k0 += 64) {
        __syncthreads();
#pragma unroll
        for (int i = 0; i < 4; i++) {
            int slot = t + 256 * i;
            int r = slot >> 3, c = (slot & 7) * 8;
            *(uint4*)&As[r * 72 + c] = *(const uint4*)&A[(size_t)(m0 + r) * K + k0 + c];
            cvt_store8(&Bs[r * 72 + c], &W[(size_t)(n0 + r) * K + k0 + c]);
        }
        __syncthreads();
#pragma unroll
        for (int ks = 0; ks < 2; ks++) {
            bf16x8 af[4], bfr[4];
            const int kc = ks * 32 + quad * 8;
#pragma unroll
            for (int mi = 0; mi < 4; mi++)
                af[mi] = *(const bf16x8*)&As[(wm + mi * 16 + l15) * 72 + kc];
#pragma unroll
            for (int ni = 0; ni < 4; ni++)
                bfr[ni] = *(const bf16x8*)&Bs[(wn + ni * 16 + l15) * 72 + kc];
#pragma unroll
            for (int ni = 0; ni < 4; ni++)
#pragma unroll
                for (int mi = 0; mi < 4; mi++)
                    acc[mi][ni] = __builtin_amdgcn_mfma_f32_16x16x32_bf16(
                        af[mi], bfr[ni], acc[mi][ni], 0, 0, 0);
        }
    }

#pragma unroll
    for (int ni = 0; ni < 4; ni++) {
        const int n = n0 + wn + ni * 16 + l15;
#pragma unroll
        for (int mi = 0; mi < 4; mi++) {
            const int gm0 = m0 + wm + mi * 16 + quad * 4;
#pragma unroll
            for (int r = 0; r < 4; r++)
                out[(size_t)(gm0 + r) * 1024 + n] = acc[mi][ni][r];
        }
    }
}

// ---------------------------------------------------------------------------
// RoPE in-place on bf16 q and k buffers, layout [bh][s][64]. One thread/pair.
// q additionally pre-scaled by 1/sqrt(HDIM)=0.125 (exact: pow-2 exponent
// shift) so attn_k skips the per-score scale.
// ---------------------------------------------------------------------------
__global__ __launch_bounds__(256)
void rope_k(ushort* __restrict__ qb, ushort* __restrict__ kb)
{
    const int idx = blockIdx.x * blockDim.x + threadIdx.x;   // BH*SEQ*32 total
    const int i  = idx & 31;
    const int s  = (idx >> 5) & 2047;
    const int bh = idx >> 16;
    ushort* buf = blockIdx.y ? kb : qb;
    const float post = blockIdx.y ? 1.0f : 0.125f;
    const size_t off = ((size_t)bh * SEQ + s) * HDIM + 2 * i;
    uint32_t pair = *(uint32_t*)&buf[off];
    float x1 = bf2f((ushort)(pair & 0xffff));
    float x2 = bf2f((ushort)(pair >> 16));
    float freq = expf(-(float)i * (9.2103403719761836f / 32.0f));  // 10000^(-i/32)
    float ang = (float)s * freq;
    float sn, cs;
    sincosf(ang, &sn, &cs);
    float o1 = (x1 * cs - x2 * sn) * post;
    float o2 = (x2 * cs + x1 * sn) * post;
    uint32_t op = (uint32_t)f2bf(o1) | ((uint32_t)f2bf(o2) << 16);
    *(uint32_t*)&buf[off] = op;
}

// ---------------------------------------------------------------------------
// Flash attention, causal — S^T formulation, occupancy-first.
// LDS: single-buffered K+V tile (18.4 KB -> 8 blocks/CU). VGPR forced <=64
// via __launch_bounds__(256,8) -> 32 waves/CU (m69: waves halve above 64).
// Register prefetch of next K/V tile across compute; 2 barriers/iter whose
// stalls are hidden by ~8 co-resident blocks.
// S^T = K*Q^T: q on lane&15 -> softmax = in-lane tree + xor16/32 shuffles.
// P^T redistributed to B-operand layout in-register (verified r4 algebra).
// Q pre-scaled by 0.125 in rope_k.
// ---------------------------------------------------------------------------
__global__ __launch_bounds__(256, 8)
void attn_k(const ushort* __restrict__ qb, const ushort* __restrict__ kb,
            const ushort* __restrict__ vt, ushort* __restrict__ ao)
{
    __shared__ ushort Ks[64 * 72];
    __shared__ ushort Vs[64 * 72];   // V^T tile: row = d, col = k_local

    const int qt = blockIdx.x;       // 0..31
    const int bh = blockIdx.y;       // 0..63
    const int q0 = qt * 64;
    const int t = threadIdx.x;
    const int lane = t & 63, wv = t >> 6;
    const int l15 = lane & 15, quad = lane >> 4;
    const int b = bh >> 4, h = bh & 15;

    // coalesced staging slots (each thread: 2 x 16B)
    const int sr0 = t >> 3, sc0 = (t & 7) * 8;   // rows 0..31
    const int sr1 = sr0 + 32;                    // rows 32..63
    const ushort* kB = kb + (size_t)bh * SEQ * HDIM;
    const ushort* vB = vt + (size_t)bh * HDIM * SEQ;

    uint4 krg[2], vrg[2];
    krg[0] = *(const uint4*)&kB[(size_t)sr0 * HDIM + sc0];
    krg[1] = *(const uint4*)&kB[(size_t)sr1 * HDIM + sc0];
    vrg[0] = *(const uint4*)&vB[(size_t)sr0 * SEQ + sc0];
    vrg[1] = *(const uint4*)&vB[(size_t)sr1 * SEQ + sc0];

    // Q fragments (B-operand of S^T) straight from global; once per block
    const int qg = q0 + wv * 16 + l15;
    const ushort* qaL = qb + ((size_t)bh * SEQ + qg) * HDIM + quad * 8;
    bf16x8 qa[2];
    qa[0] = *(const bf16x8*)(qaL);
    qa[1] = *(const bf16x8*)(qaL + 32);

    f32x4 accO[4];                // O^T: row d = mi*16+quad*4+r, col q = l15
#pragma unroll
    for (int i = 0; i < 4; i++) accO[i] = (f32x4){0.f, 0.f, 0.f, 0.f};
    float m = -30000.f, l = 0.f;

    const int qlo = (quad & 1) * 2;
    const bool hi = (quad >= 2);

    for (int kt = 0; kt <= qt; kt++) {
        const int k0 = kt * 64;
        __syncthreads();   // previous compute finished reading LDS
        *(uint4*)&Ks[sr0 * 72 + sc0] = krg[0];
        *(uint4*)&Ks[sr1 * 72 + sc0] = krg[1];
        *(uint4*)&Vs[sr0 * 72 + sc0] = vrg[0];
        *(uint4*)&Vs[sr1 * 72 + sc0] = vrg[1];
        if (kt < qt) {
            const int kn = k0 + 64;
            krg[0] = *(const uint4*)&kB[(size_t)(kn + sr0) * HDIM + sc0];
            krg[1] = *(const uint4*)&kB[(size_t)(kn + sr1) * HDIM + sc0];
            vrg[0] = *(const uint4*)&vB[(size_t)sr0 * SEQ + kn + sc0];
            vrg[1] = *(const uint4*)&vB[(size_t)sr1 * SEQ + kn + sc0];
        }
        __syncthreads();   // tile visible

        // S^T = K Q^T : st[mi] rows k = k0+mi*16+quad*4+r, col q = l15
        f32x4 st[4];
#pragma unroll
        for (int mi = 0; mi < 4; mi++) st[mi] = (f32x4){0.f, 0.f, 0.f, 0.f};
#pragma unroll
        for (int ks = 0; ks < 2; ks++) {
#pragma unroll
            for (int mi = 0; mi < 4; mi++) {
                bf16x8 ka = *(const bf16x8*)&Ks[(mi * 16 + l15) * 72 + ks * 32 + quad * 8];
                st[mi] = __builtin_amdgcn_mfma_f32_16x16x32_bf16(ka, qa[ks], st[mi], 0, 0, 0);
            }
        }

        if (kt == qt) {   // causal mask on the diagonal tile
#pragma unroll
            for (int mi = 0; mi < 4; mi++)
#pragma unroll
                for (int r = 0; r < 4; r++) {
                    int kg = k0 + mi * 16 + quad * 4 + r;
                    if (kg > qg) st[mi][r] = -30000.f;
                }
        }

        // online softmax: pairwise in-lane tree + xor16/xor32
        float a0 = fmaxf(fmaxf(st[0][0], st[0][1]), fmaxf(st[0][2], st[0][3]));
        float a1 = fmaxf(fmaxf(st[1][0], st[1][1]), fmaxf(st[1][2], st[1][3]));
        float a2 = fmaxf(fmaxf(st[2][0], st[2][1]), fmaxf(st[2][2], st[2][3]));
        float a3 = fmaxf(fmaxf(st[3][0], st[3][1]), fmaxf(st[3][2], st[3][3]));
        float mx = fmaxf(fmaxf(a0, a1), fmaxf(a2, a3));
        mx = fmaxf(mx, __shfl_xor(mx, 16));
        mx = fmaxf(mx, __shfl_xor(mx, 32));
        const float mnew = fmaxf(m, mx);
        const float alpha = __expf(m - mnew);
        float s0 = 0.f, s1 = 0.f, s2 = 0.f, s3 = 0.f;
#pragma unroll
        for (int mi = 0; mi < 4; mi++) {
            float p0 = __expf(st[mi][0] - mnew);
            float p1 = __expf(st[mi][1] - mnew);
            float p2 = __expf(st[mi][2] - mnew);
            float p3 = __expf(st[mi][3] - mnew);
            st[mi][0] = p0; st[mi][1] = p1; st[mi][2] = p2; st[mi][3] = p3;
            s0 += p0; s1 += p1; s2 += p2; s3 += p3;
        }
        float ssum = (s0 + s1) + (s2 + s3);
        ssum += __shfl_xor(ssum, 16);
        ssum += __shfl_xor(ssum, 32);
        l = l * alpha + ssum;
        m = mnew;
#pragma unroll
        for (int mi = 0; mi < 4; mi++)
#pragma unroll
            for (int r = 0; r < 4; r++) accO[mi][r] *= alpha;

        // pack P to bf16 pairs: pr[mi][w] = (k = k0+mi*16+quad*4+2w, +1)
        uint32_t pr[4][2];
#pragma unroll
        for (int mi = 0; mi < 4; mi++) {
            pr[mi][0] = pk2(st[mi][0], st[mi][1]);
            pr[mi][1] = pk2(st[mi][2], st[mi][3]);
        }

        // redistribute P^T into B-operand frags + PV MFMA (r4-verified algebra)
#pragma unroll
        for (int ks2 = 0; ks2 < 2; ks2++) {
            uint32_t pb[4];
#pragma unroll
            for (int w = 0; w < 4; w++) {
                int srcLane = (qlo + (w >> 1)) * 16 + l15;
                uint32_t va = __shfl(pr[ks2 * 2 + 0][w & 1], srcLane);
                uint32_t vb = __shfl(pr[ks2 * 2 + 1][w & 1], srcLane);
                pb[w] = hi ? vb : va;
            }
            bf16x8 pfrag;
            *(uint4*)&pfrag = *(uint4*)pb;
#pragma unroll
            for (int mi = 0; mi < 4; mi++) {
                bf16x8 vfr = *(const bf16x8*)&Vs[(mi * 16 + l15) * 72 + ks2 * 32 + quad * 8];
                accO[mi] = __builtin_amdgcn_mfma_f32_16x16x32_bf16(vfr, pfrag, accO[mi], 0, 0, 0);
            }
        }
    }

    // epilogue: O[q][d] = accO^T / l ; lane: q = qg, d = mi*16+quad*4+r
    const float rl = 1.0f / fmaxf(l, 1e-20f);
#pragma unroll
    for (int mi = 0; mi < 4; mi++) {
        uint2 o;
        o.x = pk2(accO[mi][0] * rl, accO[mi][1] * rl);
        o.y = pk2(accO[mi][2] * rl, accO[mi][3] * rl);
        *(uint2*)&ao[((size_t)(b * SEQ + qg)) * D_MODEL + h * HDIM + mi * 16 + quad * 4] = o;
    }
}

// ---------------------------------------------------------------------------
extern "C" void kernel_launch(void* const* d_in, const int* in_sizes, int n_in,
                              void* d_out, int out_size, void* d_ws, size_t ws_size,
                              hipStream_t stream)
{
    (void)out_size; (void)ws_size;
    int ix = 0, iwq = 1, iwo = 2;
    for (int i = 0; i < n_in; i++) {
        if (in_sizes[i] == 4 * SEQ * D_MODEL)          ix  = i;  // 8388608
        else if (in_sizes[i] == 3 * D_MODEL * D_MODEL) iwq = i;  // 3145728
        else if (in_sizes[i] == D_MODEL * D_MODEL)     iwo = i;  // 1048576
    }
    const float* X    = (const float*)d_in[ix];
    const float* Wqkv = (const float*)d_in[iwq];
    const float* Wout = (const float*)d_in[iwo];
    float* out = (float*)d_out;

    char* ws = (char*)d_ws;
    const size_t SZ = (size_t)BH * SEQ * HDIM * sizeof(ushort);  // 16.78 MB
    ushort* qb = (ushort*)(ws);
    ushort* kb = (ushort*)(ws + SZ);
    ushort* vt = (ushort*)(ws + 2 * SZ);
    ushort* ao = (ushort*)(ws + 3 * SZ);   // total ws use: 67.1 MB

    gemm_qkv<<<dim3(24, 64), 256, 0, stream>>>(X, Wqkv, qb, kb, vt);
    rope_k<<<dim3((BH * SEQ * 32) / 256, 2), 256, 0, stream>>>(qb, kb);
    attn_k<<<dim3(32, 64), 256, 0, stream>>>(qb, kb, vt, ao);
    gemm_out<<<dim3(8, 64), 256, 0, stream>>>(ao, Wout, out);
}

// Round 7
// 530.148 us; speedup vs baseline: 1.1409x; 1.1409x over previous
//
#include <hip/hip_runtime.h>
#include <hip/hip_bf16.h>
#include <stdint.h>

#define D_MODEL 1024
#define NHEAD   16
#define HDIM    64
#define SEQ     2048
#define BH      64   // 4 batches * 16 heads

typedef short bf16x8 __attribute__((ext_vector_type(8)));
typedef float f32x4  __attribute__((ext_vector_type(4)));

static __device__ __forceinline__ float bf2f(ushort u) {
    union { uint32_t i; float f; } v; v.i = ((uint32_t)u) << 16; return v.f;
}
static __device__ __forceinline__ ushort f2bf(float f) {
    __hip_bfloat16 h = __float2bfloat16(f);
    union { __hip_bfloat16 h; ushort u; } v; v.h = h; return v.u;
}
static __device__ __forceinline__ uint32_t pk2(float a, float b) {
    return (uint32_t)f2bf(a) | ((uint32_t)f2bf(b) << 16);
}
// Load 8 fp32, convert to bf16 (RNE), store 16B to LDS.
static __device__ __forceinline__ void cvt_store8(ushort* dst, const float* src) {
    float4 a = *(const float4*)src;
    float4 b = *(const float4*)(src + 4);
    uint4 o;
    o.x = pk2(a.x, a.y);
    o.y = pk2(a.z, a.w);
    o.z = pk2(b.x, b.y);
    o.w = pk2(b.z, b.w);
    *(uint4*)dst = o;
}

// ---------------------------------------------------------------------------
// GEMM1: qkv = X[8192,1024](f32) * Wqkv[3072,1024](f32)^T, bf16 MFMA compute.
// Scatter epilogue: q,k -> [bh][s][d] bf16 ; v -> transposed [bh][d][s] bf16.
// ---------------------------------------------------------------------------
__global__ __launch_bounds__(256)
void gemm_qkv(const float* __restrict__ X, const float* __restrict__ W,
              ushort* __restrict__ qb, ushort* __restrict__ kb,
              ushort* __restrict__ vt)
{
    __shared__ ushort As[128 * 72];
    __shared__ ushort Bs[128 * 72];
    const int K = 1024;
    const int m0 = blockIdx.y * 128;
    const int n0 = blockIdx.x * 128;
    const int t = threadIdx.x;
    const int lane = t & 63, wv = t >> 6;
    const int wm = (wv >> 1) * 64, wn = (wv & 1) * 64;
    const int l15 = lane & 15, quad = lane >> 4;

    f32x4 acc[4][4];
#pragma unroll
    for (int i = 0; i < 4; i++)
#pragma unroll
        for (int j = 0; j < 4; j++) acc[i][j] = (f32x4){0.f, 0.f, 0.f, 0.f};

    for (int k0 = 0; k0 < K; k0 += 64) {
        __syncthreads();
#pragma unroll
        for (int i = 0; i < 4; i++) {
            int slot = t + 256 * i;
            int r = slot >> 3, c = (slot & 7) * 8;
            cvt_store8(&As[r * 72 + c], &X[(size_t)(m0 + r) * K + k0 + c]);
            cvt_store8(&Bs[r * 72 + c], &W[(size_t)(n0 + r) * K + k0 + c]);
        }
        __syncthreads();
#pragma unroll
        for (int ks = 0; ks < 2; ks++) {
            bf16x8 af[4], bfr[4];
            const int kc = ks * 32 + quad * 8;
#pragma unroll
            for (int mi = 0; mi < 4; mi++)
                af[mi] = *(const bf16x8*)&As[(wm + mi * 16 + l15) * 72 + kc];
#pragma unroll
            for (int ni = 0; ni < 4; ni++)
                bfr[ni] = *(const bf16x8*)&Bs[(wn + ni * 16 + l15) * 72 + kc];
#pragma unroll
            for (int ni = 0; ni < 4; ni++)
#pragma unroll
                for (int mi = 0; mi < 4; mi++)
                    acc[mi][ni] = __builtin_amdgcn_mfma_f32_16x16x32_bf16(
                        af[mi], bfr[ni], acc[mi][ni], 0, 0, 0);
        }
    }

#pragma unroll
    for (int ni = 0; ni < 4; ni++) {
        const int e = n0 + wn + ni * 16 + l15;
        const int which = e >> 10;
        const int h = (e >> 6) & 15;
        const int d = e & 63;
#pragma unroll
        for (int mi = 0; mi < 4; mi++) {
            const int gm0 = m0 + wm + mi * 16 + quad * 4;
            const int b = gm0 >> 11;
            const int s0 = gm0 & 2047;
            const int bh = b * NHEAD + h;
            if (which == 2) {
                ushort4 pk;
                pk.x = f2bf(acc[mi][ni][0]); pk.y = f2bf(acc[mi][ni][1]);
                pk.z = f2bf(acc[mi][ni][2]); pk.w = f2bf(acc[mi][ni][3]);
                *(ushort4*)&vt[((size_t)bh * HDIM + d) * SEQ + s0] = pk;
            } else {
                ushort* dst = (which == 0) ? qb : kb;
#pragma unroll
                for (int r = 0; r < 4; r++)
                    dst[((size_t)bh * SEQ + s0 + r) * HDIM + d] = f2bf(acc[mi][ni][r]);
            }
        }
    }
}

// ---------------------------------------------------------------------------
// GEMM2: out(f32) = A[8192,1024](bf16) * Wout[1024,1024](f32)^T
// ---------------------------------------------------------------------------
__global__ __launch_bounds__(256)
void gemm_out(const ushort* __restrict__ A, const float* __restrict__ W,
              float* __restrict__ out)
{
    __shared__ ushort As[128 * 72];
    __shared__ ushort Bs[128 * 72];
    const int K = 1024;
    const int m0 = blockIdx.y * 128;
    const int n0 = blockIdx.x * 128;
    const int t = threadIdx.x;
    const int lane = t & 63, wv = t >> 6;
    const int wm = (wv >> 1) * 64, wn = (wv & 1) * 64;
    const int l15 = lane & 15, quad = lane >> 4;

    f32x4 acc[4][4];
#pragma unroll
    for (int i = 0; i < 4; i++)
#pragma unroll
        for (int j = 0; j < 4; j++) acc[i][j] = (f32x4){0.f, 0.f, 0.f, 0.f};

    for (int k0 = 0; k0 < K; k0 += 64) {
        __syncthreads();
#pragma unroll
        for (int i = 0; i < 4; i++) {
            int slot = t + 256 * i;
            int r = slot >> 3, c = (slot & 7) * 8;
            *(uint4*)&As[r * 72 + c] = *(const uint4*)&A[(size_t)(m0 + r) * K + k0 + c];
            cvt_store8(&Bs[r * 72 + c], &W[(size_t)(n0 + r) * K + k0 + c]);
        }
        __syncthreads();
#pragma unroll
        for (int ks = 0; ks < 2; ks++) {
            bf16x8 af[4], bfr[4];
            const int kc = ks * 32 + quad * 8;
#pragma unroll
            for (int mi = 0; mi < 4; mi++)
                af[mi] = *(const bf16x8*)&As[(wm + mi * 16 + l15) * 72 + kc];
#pragma unroll
            for (int ni = 0; ni < 4; ni++)
                bfr[ni] = *(const bf16x8*)&Bs[(wn + ni * 16 + l15) * 72 + kc];
#pragma unroll
            for (int ni = 0; ni < 4; ni++)
#pragma unroll
                for (int mi = 0; mi < 4; mi++)
                    acc[mi][ni] = __builtin_amdgcn_mfma_f32_16x16x32_bf16(
                        af[mi], bfr[ni], acc[mi][ni], 0, 0, 0);
        }
    }

#pragma unroll
    for (int ni = 0; ni < 4; ni++) {
        const int n = n0 + wn + ni * 16 + l15;
#pragma unroll
        for (int mi = 0; mi < 4; mi++) {
            const int gm0 = m0 + wm + mi * 16 + quad * 4;
#pragma unroll
            for (int r = 0; r < 4; r++)
                out[(size_t)(gm0 + r) * 1024 + n] = acc[mi][ni][r];
        }
    }
}

// ---------------------------------------------------------------------------
// RoPE in-place on bf16 q and k buffers, layout [bh][s][64]. One thread/pair.
// q additionally pre-scaled by 1/sqrt(HDIM)=0.125 (exact pow-2 scale).
// ---------------------------------------------------------------------------
__global__ __launch_bounds__(256)
void rope_k(ushort* __restrict__ qb, ushort* __restrict__ kb)
{
    const int idx = blockIdx.x * blockDim.x + threadIdx.x;   // BH*SEQ*32 total
    const int i  = idx & 31;
    const int s  = (idx >> 5) & 2047;
    const int bh = idx >> 16;
    ushort* buf = blockIdx.y ? kb : qb;
    const float post = blockIdx.y ? 1.0f : 0.125f;
    const size_t off = ((size_t)bh * SEQ + s) * HDIM + 2 * i;
    uint32_t pair = *(uint32_t*)&buf[off];
    float x1 = bf2f((ushort)(pair & 0xffff));
    float x2 = bf2f((ushort)(pair >> 16));
    float freq = expf(-(float)i * (9.2103403719761836f / 32.0f));  // 10000^(-i/32)
    float ang = (float)s * freq;
    float sn, cs;
    sincosf(ang, &sn, &cs);
    float o1 = (x1 * cs - x2 * sn) * post;
    float o2 = (x2 * cs + x1 * sn) * post;
    uint32_t op = (uint32_t)f2bf(o1) | ((uint32_t)f2bf(o2) << 16);
    *(uint32_t*)&buf[off] = op;
}

// ---------------------------------------------------------------------------
// Flash attention, causal — S^T formulation, occupancy-first.
// r6 structure WITHOUT the VGPR cap (r6's launch_bounds(256,8) forced
// VGPR=32 -> scratch spills, 920 MB HBM traffic). Natural allocation
// ~72-88 VGPR -> 6 waves/SIMD; LDS 18.4 KB single-buffered allows 8
// blocks/CU -> residency is VGPR-bound at ~24 waves/CU, no spills.
// S^T = K*Q^T: q on lane&15 -> softmax = in-lane tree + xor16/32 shuffles.
// P^T redistributed to B-operand layout in-register (verified r4 algebra).
// Q pre-scaled by 0.125 in rope_k.
// ---------------------------------------------------------------------------
__global__ __launch_bounds__(256)
void attn_k(const ushort* __restrict__ qb, const ushort* __restrict__ kb,
            const ushort* __restrict__ vt, ushort* __restrict__ ao)
{
    __shared__ ushort Ks[64 * 72];
    __shared__ ushort Vs[64 * 72];   // V^T tile: row = d, col = k_local

    const int qt = blockIdx.x;       // 0..31
    const int bh = blockIdx.y;       // 0..63
    const int q0 = qt * 64;
    const int t = threadIdx.x;
    const int lane = t & 63, wv = t >> 6;
    const int l15 = lane & 15, quad = lane >> 4;
    const int b = bh >> 4, h = bh & 15;

    // coalesced staging slots (each thread: 2 x 16B)
    const int sr0 = t >> 3, sc0 = (t & 7) * 8;   // rows 0..31
    const int sr1 = sr0 + 32;                    // rows 32..63
    const ushort* kB = kb + (size_t)bh * SEQ * HDIM;
    const ushort* vB = vt + (size_t)bh * HDIM * SEQ;

    uint4 krg[2], vrg[2];
    krg[0] = *(const uint4*)&kB[(size_t)sr0 * HDIM + sc0];
    krg[1] = *(const uint4*)&kB[(size_t)sr1 * HDIM + sc0];
    vrg[0] = *(const uint4*)&vB[(size_t)sr0 * SEQ + sc0];
    vrg[1] = *(const uint4*)&vB[(size_t)sr1 * SEQ + sc0];

    // Q fragments (B-operand of S^T) straight from global; once per block
    const int qg = q0 + wv * 16 + l15;
    const ushort* qaL = qb + ((size_t)bh * SEQ + qg) * HDIM + quad * 8;
    bf16x8 qa[2];
    qa[0] = *(const bf16x8*)(qaL);
    qa[1] = *(const bf16x8*)(qaL + 32);

    f32x4 accO[4];                // O^T: row d = mi*16+quad*4+r, col q = l15
#pragma unroll
    for (int i = 0; i < 4; i++) accO[i] = (f32x4){0.f, 0.f, 0.f, 0.f};
    float m = -30000.f, l = 0.f;

    const int qlo = (quad & 1) * 2;
    const bool hi = (quad >= 2);

    for (int kt = 0; kt <= qt; kt++) {
        const int k0 = kt * 64;
        __syncthreads();   // previous compute finished reading LDS
        *(uint4*)&Ks[sr0 * 72 + sc0] = krg[0];
        *(uint4*)&Ks[sr1 * 72 + sc0] = krg[1];
        *(uint4*)&Vs[sr0 * 72 + sc0] = vrg[0];
        *(uint4*)&Vs[sr1 * 72 + sc0] = vrg[1];
        if (kt < qt) {
            const int kn = k0 + 64;
            krg[0] = *(const uint4*)&kB[(size_t)(kn + sr0) * HDIM + sc0];
            krg[1] = *(const uint4*)&kB[(size_t)(kn + sr1) * HDIM + sc0];
            vrg[0] = *(const uint4*)&vB[(size_t)sr0 * SEQ + kn + sc0];
            vrg[1] = *(const uint4*)&vB[(size_t)sr1 * SEQ + kn + sc0];
        }
        __syncthreads();   // tile visible

        // S^T = K Q^T : st[mi] rows k = k0+mi*16+quad*4+r, col q = l15
        f32x4 st[4];
#pragma unroll
        for (int mi = 0; mi < 4; mi++) st[mi] = (f32x4){0.f, 0.f, 0.f, 0.f};
#pragma unroll
        for (int ks = 0; ks < 2; ks++) {
#pragma unroll
            for (int mi = 0; mi < 4; mi++) {
                bf16x8 ka = *(const bf16x8*)&Ks[(mi * 16 + l15) * 72 + ks * 32 + quad * 8];
                st[mi] = __builtin_amdgcn_mfma_f32_16x16x32_bf16(ka, qa[ks], st[mi], 0, 0, 0);
            }
        }

        if (kt == qt) {   // causal mask on the diagonal tile
#pragma unroll
            for (int mi = 0; mi < 4; mi++)
#pragma unroll
                for (int r = 0; r < 4; r++) {
                    int kg = k0 + mi * 16 + quad * 4 + r;
                    if (kg > qg) st[mi][r] = -30000.f;
                }
        }

        // online softmax: pairwise in-lane tree + xor16/xor32
        float a0 = fmaxf(fmaxf(st[0][0], st[0][1]), fmaxf(st[0][2], st[0][3]));
        float a1 = fmaxf(fmaxf(st[1][0], st[1][1]), fmaxf(st[1][2], st[1][3]));
        float a2 = fmaxf(fmaxf(st[2][0], st[2][1]), fmaxf(st[2][2], st[2][3]));
        float a3 = fmaxf(fmaxf(st[3][0], st[3][1]), fmaxf(st[3][2], st[3][3]));
        float mx = fmaxf(fmaxf(a0, a1), fmaxf(a2, a3));
        mx = fmaxf(mx, __shfl_xor(mx, 16));
        mx = fmaxf(mx, __shfl_xor(mx, 32));
        const float mnew = fmaxf(m, mx);
        const float alpha = __expf(m - mnew);
        float s0 = 0.f, s1 = 0.f, s2 = 0.f, s3 = 0.f;
#pragma unroll
        for (int mi = 0; mi < 4; mi++) {
            float p0 = __expf(st[mi][0] - mnew);
            float p1 = __expf(st[mi][1] - mnew);
            float p2 = __expf(st[mi][2] - mnew);
            float p3 = __expf(st[mi][3] - mnew);
            st[mi][0] = p0; st[mi][1] = p1; st[mi][2] = p2; st[mi][3] = p3;
            s0 += p0; s1 += p1; s2 += p2; s3 += p3;
        }
        float ssum = (s0 + s1) + (s2 + s3);
        ssum += __shfl_xor(ssum, 16);
        ssum += __shfl_xor(ssum, 32);
        l = l * alpha + ssum;
        m = mnew;
#pragma unroll
        for (int mi = 0; mi < 4; mi++)
#pragma unroll
            for (int r = 0; r < 4; r++) accO[mi][r] *= alpha;

        // pack P to bf16 pairs: pr[mi][w] = (k = k0+mi*16+quad*4+2w, +1)
        uint32_t pr[4][2];
#pragma unroll
        for (int mi = 0; mi < 4; mi++) {
            pr[mi][0] = pk2(st[mi][0], st[mi][1]);
            pr[mi][1] = pk2(st[mi][2], st[mi][3]);
        }

        // redistribute P^T into B-operand frags + PV MFMA (r4-verified algebra)
#pragma unroll
        for (int ks2 = 0; ks2 < 2; ks2++) {
            uint32_t pb[4];
#pragma unroll
            for (int w = 0; w < 4; w++) {
                int srcLane = (qlo + (w >> 1)) * 16 + l15;
                uint32_t va = __shfl(pr[ks2 * 2 + 0][w & 1], srcLane);
                uint32_t vb = __shfl(pr[ks2 * 2 + 1][w & 1], srcLane);
                pb[w] = hi ? vb : va;
            }
            bf16x8 pfrag;
            *(uint4*)&pfrag = *(uint4*)pb;
#pragma unroll
            for (int mi = 0; mi < 4; mi++) {
                bf16x8 vfr = *(const bf16x8*)&Vs[(mi * 16 + l15) * 72 + ks2 * 32 + quad * 8];
                accO[mi] = __builtin_amdgcn_mfma_f32_16x16x32_bf16(vfr, pfrag, accO[mi], 0, 0, 0);
            }
        }
    }

    // epilogue: O[q][d] = accO^T / l ; lane: q = qg, d = mi*16+quad*4+r
    const float rl = 1.0f / fmaxf(l, 1e-20f);
#pragma unroll
    for (int mi = 0; mi < 4; mi++) {
        uint2 o;
        o.x = pk2(accO[mi][0] * rl, accO[mi][1] * rl);
        o.y = pk2(accO[mi][2] * rl, accO[mi][3] * rl);
        *(uint2*)&ao[((size_t)(b * SEQ + qg)) * D_MODEL + h * HDIM + mi * 16 + quad * 4] = o;
    }
}

// ---------------------------------------------------------------------------
extern "C" void kernel_launch(void* const* d_in, const int* in_sizes, int n_in,
                              void* d_out, int out_size, void* d_ws, size_t ws_size,
                              hipStream_t stream)
{
    (void)out_size; (void)ws_size;
    int ix = 0, iwq = 1, iwo = 2;
    for (int i = 0; i < n_in; i++) {
        if (in_sizes[i] == 4 * SEQ * D_MODEL)          ix  = i;  // 8388608
        else if (in_sizes[i] == 3 * D_MODEL * D_MODEL) iwq = i;  // 3145728
        else if (in_sizes[i] == D_MODEL * D_MODEL)     iwo = i;  // 1048576
    }
    const float* X    = (const float*)d_in[ix];
    const float* Wqkv = (const float*)d_in[iwq];
    const float* Wout = (const float*)d_in[iwo];
    float* out = (float*)d_out;

    char* ws = (char*)d_ws;
    const size_t SZ = (size_t)BH * SEQ * HDIM * sizeof(ushort);  // 16.78 MB
    ushort* qb = (ushort*)(ws);
    ushort* kb = (ushort*)(ws + SZ);
    ushort* vt = (ushort*)(ws + 2 * SZ);
    ushort* ao = (ushort*)(ws + 3 * SZ);   // total ws use: 67.1 MB

    gemm_qkv<<<dim3(24, 64), 256, 0, stream>>>(X, Wqkv, qb, kb, vt);
    rope_k<<<dim3((BH * SEQ * 32) / 256, 2), 256, 0, stream>>>(qb, kb);
    attn_k<<<dim3(32, 64), 256, 0, stream>>>(qb, kb, vt, ao);
    gemm_out<<<dim3(8, 64), 256, 0, stream>>>(ao, Wout, out);
}

// Round 8
// 378.296 us; speedup vs baseline: 1.5988x; 1.4014x over previous
//
#include <hip/hip_runtime.h>
#include <hip/hip_bf16.h>
#include <stdint.h>

#define D_MODEL 1024
#define NHEAD   16
#define HDIM    64
#define SEQ     2048
#define BH      64   // 4 batches * 16 heads

typedef short bf16x8 __attribute__((ext_vector_type(8)));
typedef float f32x4  __attribute__((ext_vector_type(4)));

static __device__ __forceinline__ float bf2f(ushort u) {
    union { uint32_t i; float f; } v; v.i = ((uint32_t)u) << 16; return v.f;
}
static __device__ __forceinline__ ushort f2bf(float f) {
    __hip_bfloat16 h = __float2bfloat16(f);
    union { __hip_bfloat16 h; ushort u; } v; v.h = h; return v.u;
}
static __device__ __forceinline__ uint32_t pk2(float a, float b) {
    return (uint32_t)f2bf(a) | ((uint32_t)f2bf(b) << 16);
}
// Load 8 fp32, convert to bf16 (RNE), store 16B to LDS.
static __device__ __forceinline__ void cvt_store8(ushort* dst, const float* src) {
    float4 a = *(const float4*)src;
    float4 b = *(const float4*)(src + 4);
    uint4 o;
    o.x = pk2(a.x, a.y);
    o.y = pk2(a.z, a.w);
    o.z = pk2(b.x, b.y);
    o.w = pk2(b.z, b.w);
    *(uint4*)dst = o;
}
// Async global->LDS DMA, 16B per lane; lds dest must be wave-uniform.
static __device__ __forceinline__ void gl_lds16(const ushort* g, ushort* l) {
    __builtin_amdgcn_global_load_lds(
        (const __attribute__((address_space(1))) uint32_t*)g,
        (__attribute__((address_space(3))) uint32_t*)l, 16, 0, 0);
}

// ---------------------------------------------------------------------------
// GEMM1: qkv = X[8192,1024](f32) * Wqkv[3072,1024](f32)^T, bf16 MFMA compute.
// Scatter epilogue: q,k -> [bh][s][d] bf16 ; v -> transposed [bh][d][s] bf16.
// ---------------------------------------------------------------------------
__global__ __launch_bounds__(256)
void gemm_qkv(const float* __restrict__ X, const float* __restrict__ W,
              ushort* __restrict__ qb, ushort* __restrict__ kb,
              ushort* __restrict__ vt)
{
    __shared__ ushort As[128 * 72];
    __shared__ ushort Bs[128 * 72];
    const int K = 1024;
    const int m0 = blockIdx.y * 128;
    const int n0 = blockIdx.x * 128;
    const int t = threadIdx.x;
    const int lane = t & 63, wv = t >> 6;
    const int wm = (wv >> 1) * 64, wn = (wv & 1) * 64;
    const int l15 = lane & 15, quad = lane >> 4;

    f32x4 acc[4][4];
#pragma unroll
    for (int i = 0; i < 4; i++)
#pragma unroll
        for (int j = 0; j < 4; j++) acc[i][j] = (f32x4){0.f, 0.f, 0.f, 0.f};

    for (int k0 = 0; k0 < K; k0 += 64) {
        __syncthreads();
#pragma unroll
        for (int i = 0; i < 4; i++) {
            int slot = t + 256 * i;
            int r = slot >> 3, c = (slot & 7) * 8;
            cvt_store8(&As[r * 72 + c], &X[(size_t)(m0 + r) * K + k0 + c]);
            cvt_store8(&Bs[r * 72 + c], &W[(size_t)(n0 + r) * K + k0 + c]);
        }
        __syncthreads();
#pragma unroll
        for (int ks = 0; ks < 2; ks++) {
            bf16x8 af[4], bfr[4];
            const int kc = ks * 32 + quad * 8;
#pragma unroll
            for (int mi = 0; mi < 4; mi++)
                af[mi] = *(const bf16x8*)&As[(wm + mi * 16 + l15) * 72 + kc];
#pragma unroll
            for (int ni = 0; ni < 4; ni++)
                bfr[ni] = *(const bf16x8*)&Bs[(wn + ni * 16 + l15) * 72 + kc];
#pragma unroll
            for (int ni = 0; ni < 4; ni++)
#pragma unroll
                for (int mi = 0; mi < 4; mi++)
                    acc[mi][ni] = __builtin_amdgcn_mfma_f32_16x16x32_bf16(
                        af[mi], bfr[ni], acc[mi][ni], 0, 0, 0);
        }
    }

#pragma unroll
    for (int ni = 0; ni < 4; ni++) {
        const int e = n0 + wn + ni * 16 + l15;
        const int which = e >> 10;
        const int h = (e >> 6) & 15;
        const int d = e & 63;
#pragma unroll
        for (int mi = 0; mi < 4; mi++) {
            const int gm0 = m0 + wm + mi * 16 + quad * 4;
            const int b = gm0 >> 11;
            const int s0 = gm0 & 2047;
            const int bh = b * NHEAD + h;
            if (which == 2) {
                ushort4 pk;
                pk.x = f2bf(acc[mi][ni][0]); pk.y = f2bf(acc[mi][ni][1]);
                pk.z = f2bf(acc[mi][ni][2]); pk.w = f2bf(acc[mi][ni][3]);
                *(ushort4*)&vt[((size_t)bh * HDIM + d) * SEQ + s0] = pk;
            } else {
                ushort* dst = (which == 0) ? qb : kb;
#pragma unroll
                for (int r = 0; r < 4; r++)
                    dst[((size_t)bh * SEQ + s0 + r) * HDIM + d] = f2bf(acc[mi][ni][r]);
            }
        }
    }
}

// ---------------------------------------------------------------------------
// GEMM2: out(f32) = A[8192,1024](bf16) * Wout[1024,1024](f32)^T
// ---------------------------------------------------------------------------
__global__ __launch_bounds__(256)
void gemm_out(const ushort* __restrict__ A, const float* __restrict__ W,
              float* __restrict__ out)
{
    __shared__ ushort As[128 * 72];
    __shared__ ushort Bs[128 * 72];
    const int K = 1024;
    const int m0 = blockIdx.y * 128;
    const int n0 = blockIdx.x * 128;
    const int t = threadIdx.x;
    const int lane = t & 63, wv = t >> 6;
    const int wm = (wv >> 1) * 64, wn = (wv & 1) * 64;
    const int l15 = lane & 15, quad = lane >> 4;

    f32x4 acc[4][4];
#pragma unroll
    for (int i = 0; i < 4; i++)
#pragma unroll
        for (int j = 0; j < 4; j++) acc[i][j] = (f32x4){0.f, 0.f, 0.f, 0.f};

    for (int k0 = 0; k0 < K; k0 += 64) {
        __syncthreads();
#pragma unroll
        for (int i = 0; i < 4; i++) {
            int slot = t + 256 * i;
            int r = slot >> 3, c = (slot & 7) * 8;
            *(uint4*)&As[r * 72 + c] = *(const uint4*)&A[(size_t)(m0 + r) * K + k0 + c];
            cvt_store8(&Bs[r * 72 + c], &W[(size_t)(n0 + r) * K + k0 + c]);
        }
        __syncthreads();
#pragma unroll
        for (int ks = 0; ks < 2; ks++) {
            bf16x8 af[4], bfr[4];
            const int kc = ks * 32 + quad * 8;
#pragma unroll
            for (int mi = 0; mi < 4; mi++)
                af[mi] = *(const bf16x8*)&As[(wm + mi * 16 + l15) * 72 + kc];
#pragma unroll
            for (int ni = 0; ni < 4; ni++)
                bfr[ni] = *(const bf16x8*)&Bs[(wn + ni * 16 + l15) * 72 + kc];
#pragma unroll
            for (int ni = 0; ni < 4; ni++)
#pragma unroll
                for (int mi = 0; mi < 4; mi++)
                    acc[mi][ni] = __builtin_amdgcn_mfma_f32_16x16x32_bf16(
                        af[mi], bfr[ni], acc[mi][ni], 0, 0, 0);
        }
    }

#pragma unroll
    for (int ni = 0; ni < 4; ni++) {
        const int n = n0 + wn + ni * 16 + l15;
#pragma unroll
        for (int mi = 0; mi < 4; mi++) {
            const int gm0 = m0 + wm + mi * 16 + quad * 4;
#pragma unroll
            for (int r = 0; r < 4; r++)
                out[(size_t)(gm0 + r) * 1024 + n] = acc[mi][ni][r];
        }
    }
}

// ---------------------------------------------------------------------------
// RoPE in-place on bf16 q and k buffers, layout [bh][s][64]. One thread/pair.
// q additionally pre-scaled by 1/sqrt(HDIM)=0.125 (exact pow-2 scale).
// ---------------------------------------------------------------------------
__global__ __launch_bounds__(256)
void rope_k(ushort* __restrict__ qb, ushort* __restrict__ kb)
{
    const int idx = blockIdx.x * blockDim.x + threadIdx.x;   // BH*SEQ*32 total
    const int i  = idx & 31;
    const int s  = (idx >> 5) & 2047;
    const int bh = idx >> 16;
    ushort* buf = blockIdx.y ? kb : qb;
    const float post = blockIdx.y ? 1.0f : 0.125f;
    const size_t off = ((size_t)bh * SEQ + s) * HDIM + 2 * i;
    uint32_t pair = *(uint32_t*)&buf[off];
    float x1 = bf2f((ushort)(pair & 0xffff));
    float x2 = bf2f((ushort)(pair >> 16));
    float freq = expf(-(float)i * (9.2103403719761836f / 32.0f));  // 10000^(-i/32)
    float ang = (float)s * freq;
    float sn, cs;
    sincosf(ang, &sn, &cs);
    float o1 = (x1 * cs - x2 * sn) * post;
    float o2 = (x2 * cs + x1 * sn) * post;
    uint32_t op = (uint32_t)f2bf(o1) | ((uint32_t)f2bf(o2) << 16);
    *(uint32_t*)&buf[off] = op;
}

// ---------------------------------------------------------------------------
// Flash attention, causal — S^T formulation.
// Staging via global_load_lds DMA (no VGPR round-trip, no staging VALU):
// unpadded 64-stride rows with XOR-swizzled 16B chunks (chunk ^= row&7) —
// DMA writes are lane-contiguous; swizzled b128 reads are 2-way (free).
// LDS 16 KB. __launch_bounds__(256,6): VGPR cap ~85 vs ~68 need -> NO SPILL
// (r6: cap 8 -> VGPR32 + 523 MB spill; r7: LDS-heuristic cap -> VGPR52 +
// 158 MB spill), 24 waves/CU.
// S^T = K*Q^T: q on lane&15 -> softmax = in-lane tree + xor16/32 shuffles.
// P^T redistributed to B-operand layout in-register (verified r4 algebra).
// Q pre-scaled by 0.125 in rope_k.
// ---------------------------------------------------------------------------
__global__ __launch_bounds__(256, 6)
void attn_k(const ushort* __restrict__ qb, const ushort* __restrict__ kb,
            const ushort* __restrict__ vt, ushort* __restrict__ ao)
{
    __shared__ ushort Ks[64 * 64];
    __shared__ ushort Vs[64 * 64];   // V^T tile: row = d, col = k_local (swizzled)

    const int qt = blockIdx.x;       // 0..31
    const int bh = blockIdx.y;       // 0..63
    const int q0 = qt * 64;
    const int t = threadIdx.x;
    const int lane = t & 63, wv = t >> 6;
    const int l15 = lane & 15, quad = lane >> 4;
    const int b = bh >> 4, h = bh & 15;

    const ushort* kB = kb + (size_t)bh * SEQ * HDIM;
    const ushort* vB = vt + (size_t)bh * HDIM * SEQ;

    // DMA staging geometry: wave wv covers rows [wv*16, wv*16+16) in 2 issues.
    const int rowA = wv * 16 + (lane >> 3);
    const int cg   = (lane & 7) ^ ((lane >> 3) & 7);   // swizzled global chunk
    const int koffA = rowA * HDIM + cg * 8;            // ushort offset
    const int voffA = rowA * SEQ + cg * 8;
    ushort* ldsK = &Ks[wv * 16 * 64];                  // wave-uniform dests
    ushort* ldsV = &Vs[wv * 16 * 64];

    // swizzle-corrected LDS read offsets (same for K and V):
    //  frag(R=mi*16+l15, chunk c=ks*4+quad) lives at R*64 + (c^(l15&7))*8
    const int x7 = l15 & 7;
    const int rd0 = l15 * 64 + ((quad ^ x7) * 8);          // ks = 0
    const int rd1 = l15 * 64 + (((quad + 4) ^ x7) * 8);    // ks = 1

    // Q fragments (B-operand of S^T) straight from global; once per block
    const int qg = q0 + wv * 16 + l15;
    const ushort* qaL = qb + ((size_t)bh * SEQ + qg) * HDIM + quad * 8;
    bf16x8 qa[2];
    qa[0] = *(const bf16x8*)(qaL);
    qa[1] = *(const bf16x8*)(qaL + 32);

    f32x4 accO[4];                // O^T: row d = mi*16+quad*4+r, col q = l15
#pragma unroll
    for (int i = 0; i < 4; i++) accO[i] = (f32x4){0.f, 0.f, 0.f, 0.f};
    float m = -30000.f, l = 0.f;

    const int qlo = (quad & 1) * 2;
    const bool hi = (quad >= 2);

    for (int kt = 0; kt <= qt; kt++) {
        const int k0 = kt * 64;
        __syncthreads();   // previous compute finished reading LDS
        gl_lds16(kB + (size_t)k0 * HDIM + koffA,              ldsK);
        gl_lds16(kB + (size_t)k0 * HDIM + koffA + 8 * HDIM,   ldsK + 8 * 64);
        gl_lds16(vB + (size_t)k0 + voffA,                     ldsV);
        gl_lds16(vB + (size_t)k0 + voffA + 8 * SEQ,           ldsV + 8 * 64);
        __syncthreads();   // drains DMA; tile visible

        // S^T = K Q^T : st[mi] rows k = k0+mi*16+quad*4+r, col q = l15
        f32x4 st[4];
#pragma unroll
        for (int mi = 0; mi < 4; mi++) st[mi] = (f32x4){0.f, 0.f, 0.f, 0.f};
#pragma unroll
        for (int mi = 0; mi < 4; mi++) {
            bf16x8 ka0 = *(const bf16x8*)&Ks[mi * 1024 + rd0];
            st[mi] = __builtin_amdgcn_mfma_f32_16x16x32_bf16(ka0, qa[0], st[mi], 0, 0, 0);
        }
#pragma unroll
        for (int mi = 0; mi < 4; mi++) {
            bf16x8 ka1 = *(const bf16x8*)&Ks[mi * 1024 + rd1];
            st[mi] = __builtin_amdgcn_mfma_f32_16x16x32_bf16(ka1, qa[1], st[mi], 0, 0, 0);
        }

        if (kt == qt) {   // causal mask on the diagonal tile
#pragma unroll
            for (int mi = 0; mi < 4; mi++)
#pragma unroll
                for (int r = 0; r < 4; r++) {
                    int kg = k0 + mi * 16 + quad * 4 + r;
                    if (kg > qg) st[mi][r] = -30000.f;
                }
        }

        // online softmax: pairwise in-lane tree + xor16/xor32
        float a0 = fmaxf(fmaxf(st[0][0], st[0][1]), fmaxf(st[0][2], st[0][3]));
        float a1 = fmaxf(fmaxf(st[1][0], st[1][1]), fmaxf(st[1][2], st[1][3]));
        float a2 = fmaxf(fmaxf(st[2][0], st[2][1]), fmaxf(st[2][2], st[2][3]));
        float a3 = fmaxf(fmaxf(st[3][0], st[3][1]), fmaxf(st[3][2], st[3][3]));
        float mx = fmaxf(fmaxf(a0, a1), fmaxf(a2, a3));
        mx = fmaxf(mx, __shfl_xor(mx, 16));
        mx = fmaxf(mx, __shfl_xor(mx, 32));
        const float mnew = fmaxf(m, mx);
        const float alpha = __expf(m - mnew);
        float s0 = 0.f, s1 = 0.f, s2 = 0.f, s3 = 0.f;
#pragma unroll
        for (int mi = 0; mi < 4; mi++) {
            float p0 = __expf(st[mi][0] - mnew);
            float p1 = __expf(st[mi][1] - mnew);
            float p2 = __expf(st[mi][2] - mnew);
            float p3 = __expf(st[mi][3] - mnew);
            st[mi][0] = p0; st[mi][1] = p1; st[mi][2] = p2; st[mi][3] = p3;
            s0 += p0; s1 += p1; s2 += p2; s3 += p3;
        }
        float ssum = (s0 + s1) + (s2 + s3);
        ssum += __shfl_xor(ssum, 16);
        ssum += __shfl_xor(ssum, 32);
        l = l * alpha + ssum;
        m = mnew;
#pragma unroll
        for (int mi = 0; mi < 4; mi++)
#pragma unroll
            for (int r = 0; r < 4; r++) accO[mi][r] *= alpha;

        // pack P to bf16 pairs: pr[mi][w] = (k = k0+mi*16+quad*4+2w, +1)
        uint32_t pr[4][2];
#pragma unroll
        for (int mi = 0; mi < 4; mi++) {
            pr[mi][0] = pk2(st[mi][0], st[mi][1]);
            pr[mi][1] = pk2(st[mi][2], st[mi][3]);
        }

        // redistribute P^T into B-operand frags + PV MFMA (r4-verified algebra)
#pragma unroll
        for (int ks2 = 0; ks2 < 2; ks2++) {
            uint32_t pb[4];
#pragma unroll
            for (int w = 0; w < 4; w++) {
                int srcLane = (qlo + (w >> 1)) * 16 + l15;
                uint32_t va = __shfl(pr[ks2 * 2 + 0][w & 1], srcLane);
                uint32_t vb = __shfl(pr[ks2 * 2 + 1][w & 1], srcLane);
                pb[w] = hi ? vb : va;
            }
            bf16x8 pfrag;
            *(uint4*)&pfrag = *(uint4*)pb;
            const int rdv = ks2 ? rd1 : rd0;
#pragma unroll
            for (int mi = 0; mi < 4; mi++) {
                bf16x8 vfr = *(const bf16x8*)&Vs[mi * 1024 + rdv];
                accO[mi] = __builtin_amdgcn_mfma_f32_16x16x32_bf16(vfr, pfrag, accO[mi], 0, 0, 0);
            }
        }
    }

    // epilogue: O[q][d] = accO^T / l ; lane: q = qg, d = mi*16+quad*4+r
    const float rl = 1.0f / fmaxf(l, 1e-20f);
#pragma unroll
    for (int mi = 0; mi < 4; mi++) {
        uint2 o;
        o.x = pk2(accO[mi][0] * rl, accO[mi][1] * rl);
        o.y = pk2(accO[mi][2] * rl, accO[mi][3] * rl);
        *(uint2*)&ao[((size_t)(b * SEQ + qg)) * D_MODEL + h * HDIM + mi * 16 + quad * 4] = o;
    }
}

// ---------------------------------------------------------------------------
extern "C" void kernel_launch(void* const* d_in, const int* in_sizes, int n_in,
                              void* d_out, int out_size, void* d_ws, size_t ws_size,
                              hipStream_t stream)
{
    (void)out_size; (void)ws_size;
    int ix = 0, iwq = 1, iwo = 2;
    for (int i = 0; i < n_in; i++) {
        if (in_sizes[i] == 4 * SEQ * D_MODEL)          ix  = i;  // 8388608
        else if (in_sizes[i] == 3 * D_MODEL * D_MODEL) iwq = i;  // 3145728
        else if (in_sizes[i] == D_MODEL * D_MODEL)     iwo = i;  // 1048576
    }
    const float* X    = (const float*)d_in[ix];
    const float* Wqkv = (const float*)d_in[iwq];
    const float* Wout = (const float*)d_in[iwo];
    float* out = (float*)d_out;

    char* ws = (char*)d_ws;
    const size_t SZ = (size_t)BH * SEQ * HDIM * sizeof(ushort);  // 16.78 MB
    ushort* qb = (ushort*)(ws);
    ushort* kb = (ushort*)(ws + SZ);
    ushort* vt = (ushort*)(ws + 2 * SZ);
    ushort* ao = (ushort*)(ws + 3 * SZ);   // total ws use: 67.1 MB

    gemm_qkv<<<dim3(24, 64), 256, 0, stream>>>(X, Wqkv, qb, kb, vt);
    rope_k<<<dim3((BH * SEQ * 32) / 256, 2), 256, 0, stream>>>(qb, kb);
    attn_k<<<dim3(32, 64), 256, 0, stream>>>(qb, kb, vt, ao);
    gemm_out<<<dim3(8, 64), 256, 0, stream>>>(ao, Wout, out);
}

// Round 9
// 346.011 us; speedup vs baseline: 1.7480x; 1.0933x over previous
//
#include <hip/hip_runtime.h>
#include <hip/hip_bf16.h>
#include <stdint.h>

#define D_MODEL 1024
#define NHEAD   16
#define HDIM    64
#define SEQ     2048
#define BH      64   // 4 batches * 16 heads

typedef short bf16x8 __attribute__((ext_vector_type(8)));
typedef float f32x4  __attribute__((ext_vector_type(4)));

static __device__ __forceinline__ float bf2f(ushort u) {
    union { uint32_t i; float f; } v; v.i = ((uint32_t)u) << 16; return v.f;
}
static __device__ __forceinline__ ushort f2bf(float f) {
    __hip_bfloat16 h = __float2bfloat16(f);
    union { __hip_bfloat16 h; ushort u; } v; v.h = h; return v.u;
}
static __device__ __forceinline__ uint32_t pk2(float a, float b) {
    return (uint32_t)f2bf(a) | ((uint32_t)f2bf(b) << 16);
}
// Async global->LDS DMA, 16B per lane; lds dest must be wave-uniform.
static __device__ __forceinline__ void gl_lds16(const ushort* g, ushort* l) {
    __builtin_amdgcn_global_load_lds(
        (const __attribute__((address_space(1))) uint32_t*)g,
        (__attribute__((address_space(3))) uint32_t*)l, 16, 0, 0);
}

// ---------------------------------------------------------------------------
// fp32 -> bf16 pre-convert (RNE), 8 elems/thread. Grid sized exactly.
// ---------------------------------------------------------------------------
__global__ __launch_bounds__(256)
void cvt_k(const float* __restrict__ src, ushort* __restrict__ dst)
{
    const size_t i = ((size_t)blockIdx.x * 256 + threadIdx.x) * 8;
    float4 a = *(const float4*)&src[i];
    float4 b = *(const float4*)&src[i + 4];
    uint4 o;
    o.x = pk2(a.x, a.y);
    o.y = pk2(a.z, a.w);
    o.z = pk2(b.x, b.y);
    o.w = pk2(b.z, b.w);
    *(uint4*)&dst[i] = o;
}

// ---------------------------------------------------------------------------
// GEMM1: qkv = Xb[8192,1024](bf16) * Wb[3072,1024](bf16)^T.
// Staging via global_load_lds DMA, XOR-swizzled unpadded 64-stride rows
// (r8-verified pattern). Scatter epilogue: q,k -> [bh][s][d]; v -> [bh][d][s].
// ---------------------------------------------------------------------------
__global__ __launch_bounds__(256)
void gemm_qkv(const ushort* __restrict__ Xb, const ushort* __restrict__ Wb,
              ushort* __restrict__ qb, ushort* __restrict__ kb,
              ushort* __restrict__ vt)
{
    __shared__ ushort As[128 * 64];
    __shared__ ushort Bs[128 * 64];
    const int K = 1024;
    const int m0 = blockIdx.y * 128;
    const int n0 = blockIdx.x * 128;
    const int t = threadIdx.x;
    const int lane = t & 63, wv = t >> 6;
    const int wm = (wv >> 1) * 64, wn = (wv & 1) * 64;
    const int l15 = lane & 15, quad = lane >> 4;

    // DMA geometry: per issue a wave stages 8 rows (lane>>3) x 8 chunks.
    const int rsub = lane >> 3;
    const int cg   = (lane & 7) ^ rsub;            // swizzled global chunk
    // swizzle-corrected read offsets (chunk c = ks*4+quad), mi-independent:
    const int x7  = l15 & 7;
    const int rdk[2] = { ((quad ^ x7) * 8), (((quad + 4) ^ x7) * 8) };

    f32x4 acc[4][4];
#pragma unroll
    for (int i = 0; i < 4; i++)
#pragma unroll
        for (int j = 0; j < 4; j++) acc[i][j] = (f32x4){0.f, 0.f, 0.f, 0.f};

    for (int k0 = 0; k0 < K; k0 += 64) {
        __syncthreads();
#pragma unroll
        for (int i = 0; i < 4; i++) {
            const int rbase = i * 32 + wv * 8;
            gl_lds16(&Xb[(size_t)(m0 + rbase + rsub) * K + k0 + cg * 8], &As[rbase * 64]);
            gl_lds16(&Wb[(size_t)(n0 + rbase + rsub) * K + k0 + cg * 8], &Bs[rbase * 64]);
        }
        __syncthreads();
#pragma unroll
        for (int ks = 0; ks < 2; ks++) {
            bf16x8 af[4], bfr[4];
#pragma unroll
            for (int mi = 0; mi < 4; mi++)
                af[mi] = *(const bf16x8*)&As[(wm + mi * 16 + l15) * 64 + rdk[ks]];
#pragma unroll
            for (int ni = 0; ni < 4; ni++)
                bfr[ni] = *(const bf16x8*)&Bs[(wn + ni * 16 + l15) * 64 + rdk[ks]];
#pragma unroll
            for (int ni = 0; ni < 4; ni++)
#pragma unroll
                for (int mi = 0; mi < 4; mi++)
                    acc[mi][ni] = __builtin_amdgcn_mfma_f32_16x16x32_bf16(
                        af[mi], bfr[ni], acc[mi][ni], 0, 0, 0);
        }
    }

#pragma unroll
    for (int ni = 0; ni < 4; ni++) {
        const int e = n0 + wn + ni * 16 + l15;
        const int which = e >> 10;
        const int h = (e >> 6) & 15;
        const int d = e & 63;
#pragma unroll
        for (int mi = 0; mi < 4; mi++) {
            const int gm0 = m0 + wm + mi * 16 + quad * 4;
            const int b = gm0 >> 11;
            const int s0 = gm0 & 2047;
            const int bh = b * NHEAD + h;
            if (which == 2) {
                ushort4 pk;
                pk.x = f2bf(acc[mi][ni][0]); pk.y = f2bf(acc[mi][ni][1]);
                pk.z = f2bf(acc[mi][ni][2]); pk.w = f2bf(acc[mi][ni][3]);
                *(ushort4*)&vt[((size_t)bh * HDIM + d) * SEQ + s0] = pk;
            } else {
                ushort* dst = (which == 0) ? qb : kb;
#pragma unroll
                for (int r = 0; r < 4; r++)
                    dst[((size_t)bh * SEQ + s0 + r) * HDIM + d] = f2bf(acc[mi][ni][r]);
            }
        }
    }
}

// ---------------------------------------------------------------------------
// GEMM2: out(f32) = A[8192,1024](bf16) * Wb[1024,1024](bf16)^T — DMA staging.
// ---------------------------------------------------------------------------
__global__ __launch_bounds__(256)
void gemm_out(const ushort* __restrict__ A, const ushort* __restrict__ Wb,
              float* __restrict__ out)
{
    __shared__ ushort As[128 * 64];
    __shared__ ushort Bs[128 * 64];
    const int K = 1024;
    const int m0 = blockIdx.y * 128;
    const int n0 = blockIdx.x * 128;
    const int t = threadIdx.x;
    const int lane = t & 63, wv = t >> 6;
    const int wm = (wv >> 1) * 64, wn = (wv & 1) * 64;
    const int l15 = lane & 15, quad = lane >> 4;

    const int rsub = lane >> 3;
    const int cg   = (lane & 7) ^ rsub;
    const int x7  = l15 & 7;
    const int rdk[2] = { ((quad ^ x7) * 8), (((quad + 4) ^ x7) * 8) };

    f32x4 acc[4][4];
#pragma unroll
    for (int i = 0; i < 4; i++)
#pragma unroll
        for (int j = 0; j < 4; j++) acc[i][j] = (f32x4){0.f, 0.f, 0.f, 0.f};

    for (int k0 = 0; k0 < K; k0 += 64) {
        __syncthreads();
#pragma unroll
        for (int i = 0; i < 4; i++) {
            const int rbase = i * 32 + wv * 8;
            gl_lds16(&A[(size_t)(m0 + rbase + rsub) * K + k0 + cg * 8],  &As[rbase * 64]);
            gl_lds16(&Wb[(size_t)(n0 + rbase + rsub) * K + k0 + cg * 8], &Bs[rbase * 64]);
        }
        __syncthreads();
#pragma unroll
        for (int ks = 0; ks < 2; ks++) {
            bf16x8 af[4], bfr[4];
#pragma unroll
            for (int mi = 0; mi < 4; mi++)
                af[mi] = *(const bf16x8*)&As[(wm + mi * 16 + l15) * 64 + rdk[ks]];
#pragma unroll
            for (int ni = 0; ni < 4; ni++)
                bfr[ni] = *(const bf16x8*)&Bs[(wn + ni * 16 + l15) * 64 + rdk[ks]];
#pragma unroll
            for (int ni = 0; ni < 4; ni++)
#pragma unroll
                for (int mi = 0; mi < 4; mi++)
                    acc[mi][ni] = __builtin_amdgcn_mfma_f32_16x16x32_bf16(
                        af[mi], bfr[ni], acc[mi][ni], 0, 0, 0);
        }
    }

#pragma unroll
    for (int ni = 0; ni < 4; ni++) {
        const int n = n0 + wn + ni * 16 + l15;
#pragma unroll
        for (int mi = 0; mi < 4; mi++) {
            const int gm0 = m0 + wm + mi * 16 + quad * 4;
#pragma unroll
            for (int r = 0; r < 4; r++)
                out[(size_t)(gm0 + r) * 1024 + n] = acc[mi][ni][r];
        }
    }
}

// ---------------------------------------------------------------------------
// RoPE in-place on bf16 q and k buffers, layout [bh][s][64]. One thread/pair.
// q additionally pre-scaled by 1/sqrt(HDIM)=0.125 (exact pow-2 scale).
// ---------------------------------------------------------------------------
__global__ __launch_bounds__(256)
void rope_k(ushort* __restrict__ qb, ushort* __restrict__ kb)
{
    const int idx = blockIdx.x * blockDim.x + threadIdx.x;   // BH*SEQ*32 total
    const int i  = idx & 31;
    const int s  = (idx >> 5) & 2047;
    const int bh = idx >> 16;
    ushort* buf = blockIdx.y ? kb : qb;
    const float post = blockIdx.y ? 1.0f : 0.125f;
    const size_t off = ((size_t)bh * SEQ + s) * HDIM + 2 * i;
    uint32_t pair = *(uint32_t*)&buf[off];
    float x1 = bf2f((ushort)(pair & 0xffff));
    float x2 = bf2f((ushort)(pair >> 16));
    float freq = expf(-(float)i * (9.2103403719761836f / 32.0f));  // 10000^(-i/32)
    float ang = (float)s * freq;
    float sn, cs;
    sincosf(ang, &sn, &cs);
    float o1 = (x1 * cs - x2 * sn) * post;
    float o2 = (x2 * cs + x1 * sn) * post;
    uint32_t op = (uint32_t)f2bf(o1) | ((uint32_t)f2bf(o2) << 16);
    *(uint32_t*)&buf[off] = op;
}

// ---------------------------------------------------------------------------
// Flash attention, causal — S^T formulation. (r8 kernel, unchanged.)
// ---------------------------------------------------------------------------
__global__ __launch_bounds__(256, 6)
void attn_k(const ushort* __restrict__ qb, const ushort* __restrict__ kb,
            const ushort* __restrict__ vt, ushort* __restrict__ ao)
{
    __shared__ ushort Ks[64 * 64];
    __shared__ ushort Vs[64 * 64];   // V^T tile: row = d, col = k_local (swizzled)

    const int qt = blockIdx.x;       // 0..31
    const int bh = blockIdx.y;       // 0..63
    const int q0 = qt * 64;
    const int t = threadIdx.x;
    const int lane = t & 63, wv = t >> 6;
    const int l15 = lane & 15, quad = lane >> 4;
    const int b = bh >> 4, h = bh & 15;

    const ushort* kB = kb + (size_t)bh * SEQ * HDIM;
    const ushort* vB = vt + (size_t)bh * HDIM * SEQ;

    const int rowA = wv * 16 + (lane >> 3);
    const int cg   = (lane & 7) ^ ((lane >> 3) & 7);
    const int koffA = rowA * HDIM + cg * 8;
    const int voffA = rowA * SEQ + cg * 8;
    ushort* ldsK = &Ks[wv * 16 * 64];
    ushort* ldsV = &Vs[wv * 16 * 64];

    const int x7 = l15 & 7;
    const int rd0 = l15 * 64 + ((quad ^ x7) * 8);
    const int rd1 = l15 * 64 + (((quad + 4) ^ x7) * 8);

    const int qg = q0 + wv * 16 + l15;
    const ushort* qaL = qb + ((size_t)bh * SEQ + qg) * HDIM + quad * 8;
    bf16x8 qa[2];
    qa[0] = *(const bf16x8*)(qaL);
    qa[1] = *(const bf16x8*)(qaL + 32);

    f32x4 accO[4];
#pragma unroll
    for (int i = 0; i < 4; i++) accO[i] = (f32x4){0.f, 0.f, 0.f, 0.f};
    float m = -30000.f, l = 0.f;

    const int qlo = (quad & 1) * 2;
    const bool hi = (quad >= 2);

    for (int kt = 0; kt <= qt; kt++) {
        const int k0 = kt * 64;
        __syncthreads();
        gl_lds16(kB + (size_t)k0 * HDIM + koffA,              ldsK);
        gl_lds16(kB + (size_t)k0 * HDIM + koffA + 8 * HDIM,   ldsK + 8 * 64);
        gl_lds16(vB + (size_t)k0 + voffA,                     ldsV);
        gl_lds16(vB + (size_t)k0 + voffA + 8 * SEQ,           ldsV + 8 * 64);
        __syncthreads();

        f32x4 st[4];
#pragma unroll
        for (int mi = 0; mi < 4; mi++) st[mi] = (f32x4){0.f, 0.f, 0.f, 0.f};
#pragma unroll
        for (int mi = 0; mi < 4; mi++) {
            bf16x8 ka0 = *(const bf16x8*)&Ks[mi * 1024 + rd0];
            st[mi] = __builtin_amdgcn_mfma_f32_16x16x32_bf16(ka0, qa[0], st[mi], 0, 0, 0);
        }
#pragma unroll
        for (int mi = 0; mi < 4; mi++) {
            bf16x8 ka1 = *(const bf16x8*)&Ks[mi * 1024 + rd1];
            st[mi] = __builtin_amdgcn_mfma_f32_16x16x32_bf16(ka1, qa[1], st[mi], 0, 0, 0);
        }

        if (kt == qt) {
#pragma unroll
            for (int mi = 0; mi < 4; mi++)
#pragma unroll
                for (int r = 0; r < 4; r++) {
                    int kg = k0 + mi * 16 + quad * 4 + r;
                    if (kg > qg) st[mi][r] = -30000.f;
                }
        }

        float a0 = fmaxf(fmaxf(st[0][0], st[0][1]), fmaxf(st[0][2], st[0][3]));
        float a1 = fmaxf(fmaxf(st[1][0], st[1][1]), fmaxf(st[1][2], st[1][3]));
        float a2 = fmaxf(fmaxf(st[2][0], st[2][1]), fmaxf(st[2][2], st[2][3]));
        float a3 = fmaxf(fmaxf(st[3][0], st[3][1]), fmaxf(st[3][2], st[3][3]));
        float mx = fmaxf(fmaxf(a0, a1), fmaxf(a2, a3));
        mx = fmaxf(mx, __shfl_xor(mx, 16));
        mx = fmaxf(mx, __shfl_xor(mx, 32));
        const float mnew = fmaxf(m, mx);
        const float alpha = __expf(m - mnew);
        float s0 = 0.f, s1 = 0.f, s2 = 0.f, s3 = 0.f;
#pragma unroll
        for (int mi = 0; mi < 4; mi++) {
            float p0 = __expf(st[mi][0] - mnew);
            float p1 = __expf(st[mi][1] - mnew);
            float p2 = __expf(st[mi][2] - mnew);
            float p3 = __expf(st[mi][3] - mnew);
            st[mi][0] = p0; st[mi][1] = p1; st[mi][2] = p2; st[mi][3] = p3;
            s0 += p0; s1 += p1; s2 += p2; s3 += p3;
        }
        float ssum = (s0 + s1) + (s2 + s3);
        ssum += __shfl_xor(ssum, 16);
        ssum += __shfl_xor(ssum, 32);
        l = l * alpha + ssum;
        m = mnew;
#pragma unroll
        for (int mi = 0; mi < 4; mi++)
#pragma unroll
            for (int r = 0; r < 4; r++) accO[mi][r] *= alpha;

        uint32_t pr[4][2];
#pragma unroll
        for (int mi = 0; mi < 4; mi++) {
            pr[mi][0] = pk2(st[mi][0], st[mi][1]);
            pr[mi][1] = pk2(st[mi][2], st[mi][3]);
        }

#pragma unroll
        for (int ks2 = 0; ks2 < 2; ks2++) {
            uint32_t pb[4];
#pragma unroll
            for (int w = 0; w < 4; w++) {
                int srcLane = (qlo + (w >> 1)) * 16 + l15;
                uint32_t va = __shfl(pr[ks2 * 2 + 0][w & 1], srcLane);
                uint32_t vb = __shfl(pr[ks2 * 2 + 1][w & 1], srcLane);
                pb[w] = hi ? vb : va;
            }
            bf16x8 pfrag;
            *(uint4*)&pfrag = *(uint4*)pb;
            const int rdv = ks2 ? rd1 : rd0;
#pragma unroll
            for (int mi = 0; mi < 4; mi++) {
                bf16x8 vfr = *(const bf16x8*)&Vs[mi * 1024 + rdv];
                accO[mi] = __builtin_amdgcn_mfma_f32_16x16x32_bf16(vfr, pfrag, accO[mi], 0, 0, 0);
            }
        }
    }

    const float rl = 1.0f / fmaxf(l, 1e-20f);
#pragma unroll
    for (int mi = 0; mi < 4; mi++) {
        uint2 o;
        o.x = pk2(accO[mi][0] * rl, accO[mi][1] * rl);
        o.y = pk2(accO[mi][2] * rl, accO[mi][3] * rl);
        *(uint2*)&ao[((size_t)(b * SEQ + qg)) * D_MODEL + h * HDIM + mi * 16 + quad * 4] = o;
    }
}

// ---------------------------------------------------------------------------
extern "C" void kernel_launch(void* const* d_in, const int* in_sizes, int n_in,
                              void* d_out, int out_size, void* d_ws, size_t ws_size,
                              hipStream_t stream)
{
    (void)out_size; (void)ws_size;
    int ix = 0, iwq = 1, iwo = 2;
    for (int i = 0; i < n_in; i++) {
        if (in_sizes[i] == 4 * SEQ * D_MODEL)          ix  = i;  // 8388608
        else if (in_sizes[i] == 3 * D_MODEL * D_MODEL) iwq = i;  // 3145728
        else if (in_sizes[i] == D_MODEL * D_MODEL)     iwo = i;  // 1048576
    }
    const float* X    = (const float*)d_in[ix];
    const float* Wqkv = (const float*)d_in[iwq];
    const float* Wout = (const float*)d_in[iwo];
    float* out = (float*)d_out;

    char* ws = (char*)d_ws;
    const size_t SZ = (size_t)BH * SEQ * HDIM * sizeof(ushort);  // 16.78 MB
    ushort* xb = (ushort*)(ws);            // X in bf16; reused as ao after gemm_qkv
    ushort* qb = (ushort*)(ws + SZ);
    ushort* kb = (ushort*)(ws + 2 * SZ);
    ushort* vt = (ushort*)(ws + 3 * SZ);
    ushort* wqb = (ushort*)(ws + 4 * SZ);                        // 6.29 MB
    ushort* wob = (ushort*)(ws + 4 * SZ + 3 * (size_t)D_MODEL * D_MODEL * 2);
    ushort* ao = xb;                       // alias: xb dead after gemm_qkv

    cvt_k<<<dim3(4096), 256, 0, stream>>>(X, xb);
    cvt_k<<<dim3(1536), 256, 0, stream>>>(Wqkv, wqb);
    cvt_k<<<dim3(512),  256, 0, stream>>>(Wout, wob);
    gemm_qkv<<<dim3(24, 64), 256, 0, stream>>>(xb, wqb, qb, kb, vt);
    rope_k<<<dim3((BH * SEQ * 32) / 256, 2), 256, 0, stream>>>(qb, kb);
    attn_k<<<dim3(32, 64), 256, 0, stream>>>(qb, kb, vt, ao);
    gemm_out<<<dim3(8, 64), 256, 0, stream>>>(ao, wob, out);
}